// Round 9
// baseline (127.771 us; speedup 1.0000x reference)
//
#include <hip/hip_runtime.h>
#include <hip/hip_fp16.h>
#include <hip/hip_cooperative_groups.h>

namespace cg = cooperative_groups;

// EdgePredictor: score = sigmoid(dot(h[src], h[dst])) for 2M edges.
// R9: single cooperative kernel (2048 blocks co-resident):
//   phase 1: 977 scatter blocks || 1071 convert blocks (true overlap, all
//            resident from t=0); grid.sync();
//   phase 2: main gather as 16-iter loop, XCD-contiguous slot mapping
//            (bid&7 = XCD under round-robin dispatch).
// Removes 2 launch gaps + phase-tail slack vs R8 (non-main was ~39us,
// byte floor ~25us). Main phase is at the ~3.5TB/s random-256B-granule
// fabric wall (Little's-law check R8) -- untouched logic.
// Fallback: R8's 3-dispatch path if cooperative launch unavailable/fails.

#define N_NODES 100000
#define D_FEAT  128
#define N_EDGES 1000000
#define NTOT    (2 * N_EDGES)
#define NB      32
#define BLOCK_ROWS ((N_NODES + NB - 1) / NB)   // 3125
#define CAP     65536                           // slots/bucket (pow2)
#define NSLOTS  (NB * CAP)                      // 2,097,152

#define CURSOR_OFF 256                          // int[32]
#define H16_OFF    4096
#define H16_BYTES  ((size_t)N_NODES * D_FEAT * 2)      // 25,600,000
#define PACKED_OFF (H16_OFF + H16_BYTES)                // 16B-aligned
#define PACKED_BYTES ((size_t)NSLOTS * 8)               // 16.8 MB
#define WS_NEED    (PACKED_OFF + PACKED_BYTES)          // ~42.4 MB

#define CONV_ITEMS  (N_NODES * D_FEAT / 8)              // 1,600,000
#define CONV_BLOCKS (CONV_ITEMS / 256)                  // 6250
#define SORT_GRID   ((NTOT + 2047) / 2048)              // 977
#define COOP_BLOCKS 2048

typedef float f4v __attribute__((ext_vector_type(4)));

__device__ __forceinline__ int detect64(const void* ea) {
    const long long* p = (const long long*)ea;
    int is64 = 1;
    #pragma unroll
    for (int i = 0; i < 8; ++i) {
        long long v = p[i];
        if (v < 0 || v >= N_NODES) is64 = 0;
    }
    return is64;
}

__device__ __forceinline__ void load_edge(const void* ea, const void* eb,
                                          int is64, long long e,
                                          int& s, int& d) {
    if (e < N_EDGES) {
        if (is64) {
            s = (int)((const long long*)ea)[e];
            d = (int)((const long long*)ea)[e + N_EDGES];
        } else {
            s = ((const int*)ea)[e];
            d = ((const int*)ea)[e + N_EDGES];
        }
    } else {
        long long e2 = e - N_EDGES;
        if (is64) {
            s = (int)((const long long*)eb)[e2];
            d = (int)((const long long*)eb)[e2 + N_EDGES];
        } else {
            s = ((const int*)eb)[e2];
            d = ((const int*)eb)[e2 + N_EDGES];
        }
    }
}

__device__ __forceinline__ void convert8(const float* __restrict__ h,
                                         __half* __restrict__ hh, int i) {
    const float4* src = (const float4*)h;
    float4 a = src[2 * i];
    float4 b = src[2 * i + 1];
    __half2 r[4];
    r[0] = __float22half2_rn(make_float2(a.x, a.y));
    r[1] = __float22half2_rn(make_float2(a.z, a.w));
    r[2] = __float22half2_rn(make_float2(b.x, b.y));
    r[3] = __float22half2_rn(make_float2(b.z, b.w));
    ((float4*)hh)[i] = *(const float4*)r;
}

__device__ __forceinline__ float dot8_f16(f4v sv, f4v dv, float acc) {
    const __half2* s2 = (const __half2*)&sv;
    const __half2* d2 = (const __half2*)&dv;
#if __has_builtin(__builtin_amdgcn_fdot2)
    #pragma unroll
    for (int j = 0; j < 4; ++j)
        acc = __builtin_amdgcn_fdot2(s2[j], d2[j], acc, false);
#else
    #pragma unroll
    for (int j = 0; j < 4; ++j) {
        float2 sf = __half22float2(s2[j]);
        float2 df = __half22float2(d2[j]);
        acc += sf.x * df.x + sf.y * df.y;
    }
#endif
    return acc;
}

__device__ __forceinline__ void scatter_chunk(
    const void* ea, const void* eb, int sidx,
    int* cursor, unsigned long long* packed,
    int* lh, int* lcur, int tid) {
    if (tid < NB) lh[tid] = 0;
    __syncthreads();
    const int is64 = detect64(ea);
    long long base = (long long)sidx * 2048;
    int ss[8], dd[8], ee[8];
    int cnt = 0;
    #pragma unroll
    for (int i = 0; i < 8; ++i) {
        long long e = base + i * 256 + tid;
        if (e >= NTOT) break;
        int s, d;
        load_edge(ea, eb, is64, e, s, d);
        ss[cnt] = s; dd[cnt] = d; ee[cnt] = (int)e; ++cnt;
        atomicAdd(&lh[s / BLOCK_ROWS], 1);
    }
    __syncthreads();
    if (tid < NB)
        lcur[tid] = tid * CAP + atomicAdd(&cursor[tid], lh[tid]);
    __syncthreads();
    for (int i = 0; i < cnt; ++i) {
        int b = ss[i] / BLOCK_ROWS;
        int pos = atomicAdd(&lcur[b], 1);
        packed[pos] = (unsigned long long)ss[i]
                    | ((unsigned long long)dd[i] << 17)
                    | ((unsigned long long)ee[i] << 34);
    }
}

__device__ __forceinline__ void main_pair(
    const __half* __restrict__ hh,
    const unsigned long long* __restrict__ packed,
    float* __restrict__ out, int slot0, int cb, int lane) {
    int l0 = slot0 & (CAP - 1);
    if (l0 >= cb) return;
    bool v1 = (l0 + 1) < cb;
    ulonglong2 pp = *(const ulonglong2*)(packed + slot0);
    unsigned long long p0 = pp.x;
    unsigned long long p1 = v1 ? pp.y : pp.x;
    int s0 = (int)(p0 & 0x1FFFF), d0 = (int)((p0 >> 17) & 0x1FFFF), e0 = (int)(p0 >> 34);
    int s1 = (int)(p1 & 0x1FFFF), d1 = (int)((p1 >> 17) & 0x1FFFF), e1 = (int)(p1 >> 34);

    const f4v* ps0 = (const f4v*)(hh + (size_t)s0 * D_FEAT) + lane * 2;
    const f4v* pd0 = (const f4v*)(hh + (size_t)d0 * D_FEAT) + lane * 2;
    const f4v* ps1 = (const f4v*)(hh + (size_t)s1 * D_FEAT) + lane * 2;
    const f4v* pd1 = (const f4v*)(hh + (size_t)d1 * D_FEAT) + lane * 2;
    f4v sa0 = ps0[0], sb0 = ps0[1];
    f4v da0 = pd0[0], db0 = pd0[1];
    f4v sa1 = ps1[0], sb1 = ps1[1];
    f4v da1 = pd1[0], db1 = pd1[1];

    float acc0 = dot8_f16(sb0, db0, dot8_f16(sa0, da0, 0.0f));
    float acc1 = dot8_f16(sb1, db1, dot8_f16(sa1, da1, 0.0f));
    acc0 += __shfl_xor(acc0, 4, 64);
    acc0 += __shfl_xor(acc0, 2, 64);
    acc0 += __shfl_xor(acc0, 1, 64);
    acc1 += __shfl_xor(acc1, 4, 64);
    acc1 += __shfl_xor(acc1, 2, 64);
    acc1 += __shfl_xor(acc1, 1, 64);

    if (lane == 0) {
        out[e0] = 1.0f / (1.0f + expf(-acc0));
        if (v1) out[e1] = 1.0f / (1.0f + expf(-acc1));
    }
}

// ---- cooperative fused kernel ----
__global__ __launch_bounds__(256, 8) void fused_all(
    const float* __restrict__ h, __half* __restrict__ hh,
    const void* __restrict__ ea, const void* __restrict__ eb,
    int* __restrict__ cursor, unsigned long long* __restrict__ packed,
    float* __restrict__ out) {
    __shared__ int lh[NB];
    __shared__ int lcur[NB];
    int bid = blockIdx.x;
    int tid = threadIdx.x;

    // ---- phase 1: scatter (blocks 0..976) || convert (blocks 977..2047) ----
    if (bid < SORT_GRID) {
        scatter_chunk(ea, eb, bid, cursor, packed, lh, lcur, tid);
    } else {
        const int stride = (COOP_BLOCKS - SORT_GRID) * 256;  // 274176
        for (int i = (bid - SORT_GRID) * 256 + tid; i < CONV_ITEMS; i += stride)
            convert8(h, hh, i);
    }

    cg::this_grid().sync();

    // ---- phase 2: main gather, 16 iterations, XCD-contiguous slots ----
    int x = bid & 7;                 // XCD under round-robin dispatch
    int inner = bid >> 3;            // 0..255
    int g = tid >> 3, lane = tid & 7;
    #pragma unroll 1
    for (int t = 0; t < 16; ++t) {
        int vb = x * 4096 + t * 256 + inner;
        int slot0 = vb * 64 + g * 2;
        int b = slot0 >> 16;
        main_pair(hh, packed, out, slot0, cursor[b], lane);
    }
}

// ======== fallback path (R8): memset + pre + main, 3 dispatches ========
__global__ __launch_bounds__(256) void pre_kernel(
    const float* __restrict__ h, __half* __restrict__ hh,
    const void* __restrict__ ea, const void* __restrict__ eb,
    int* __restrict__ cursor, unsigned long long* __restrict__ packed) {
    __shared__ int lh[NB];
    __shared__ int lcur[NB];
    int bid = blockIdx.x;
    int tid = threadIdx.x;
    int grp = bid >> 6;
    int sub = bid & 63;
    if (sub >= 8) {
        int cidx = grp * 56 + sub - 8;
        if (cidx >= CONV_BLOCKS) return;
        convert8(h, hh, cidx * 256 + tid);
        return;
    }
    int sidx = grp * 8 + sub;
    if (sidx >= SORT_GRID) return;
    scatter_chunk(ea, eb, sidx, cursor, packed, lh, lcur, tid);
}

#define PRE_GROUPS 123
#define PRE_GRID   (PRE_GROUPS * 64)
#define MAIN_GRID (NSLOTS / 64)                // 32768 blocks
#define GRID_PER_XCD (MAIN_GRID / 8)           // 4096

__global__ __launch_bounds__(256) void edge_main_sorted(
    const __half* __restrict__ hh,
    const unsigned long long* __restrict__ packed,
    const int* __restrict__ cnt,
    float* __restrict__ out) {
    int bid = blockIdx.x;
    int swz = (bid & 7) * GRID_PER_XCD + (bid >> 3);
    int gid = swz * 256 + threadIdx.x;
    int grp  = gid >> 3;
    int lane = gid & 7;
    int slot0 = grp << 1;
    int b = slot0 >> 16;
    main_pair(hh, packed, out, slot0, cnt[b], lane);
}

// ---- fallback (ws fits h16 only): unsorted fp16 ----
__global__ __launch_bounds__(256) void convert_h_fp16(
    const float* __restrict__ h, __half* __restrict__ hh) {
    int i = blockIdx.x * 256 + threadIdx.x;
    if (i >= CONV_ITEMS) return;
    convert8(h, hh, i);
}

__global__ __launch_bounds__(256) void edge_pred_fp16(
    const __half* __restrict__ hh,
    const void* __restrict__ ea, const void* __restrict__ eb,
    float* __restrict__ out) {
    int gid  = blockIdx.x * 256 + threadIdx.x;
    int edge = gid >> 3;
    int lane = gid & 7;
    if (edge >= NTOT) return;
    const int is64 = detect64(ea);
    int s, d;
    load_edge(ea, eb, is64, (long long)edge, s, d);
    const f4v* ps = (const f4v*)(hh + (size_t)s * D_FEAT) + lane * 2;
    const f4v* pd = (const f4v*)(hh + (size_t)d * D_FEAT) + lane * 2;
    f4v s0 = ps[0], s1 = ps[1], d0 = pd[0], d1 = pd[1];
    float acc = dot8_f16(s1, d1, dot8_f16(s0, d0, 0.0f));
    acc += __shfl_xor(acc, 4, 64);
    acc += __shfl_xor(acc, 2, 64);
    acc += __shfl_xor(acc, 1, 64);
    if (lane == 0)
        out[edge] = 1.0f / (1.0f + expf(-acc));
}

// ---- fallback (no ws): fp32 ----
__global__ __launch_bounds__(256) void edge_pred_fp32(
    const float* __restrict__ h,
    const void* __restrict__ ea, const void* __restrict__ eb,
    float* __restrict__ out) {
    int gid  = blockIdx.x * 256 + threadIdx.x;
    int edge = gid >> 4;
    int lane = gid & 15;
    if (edge >= NTOT) return;
    const int is64 = detect64(ea);
    int s, d;
    load_edge(ea, eb, is64, (long long)edge, s, d);
    const float4* ps = (const float4*)(h + (size_t)s * D_FEAT) + lane * 2;
    const float4* pd = (const float4*)(h + (size_t)d * D_FEAT) + lane * 2;
    float4 s0 = ps[0], s1 = ps[1], d0 = pd[0], d1 = pd[1];
    float acc = s0.x * d0.x + s0.y * d0.y + s0.z * d0.z + s0.w * d0.w
              + s1.x * d1.x + s1.y * d1.y + s1.z * d1.z + s1.w * d1.w;
    #pragma unroll
    for (int off = 8; off >= 1; off >>= 1)
        acc += __shfl_xor(acc, off, 64);
    if (lane == 0)
        out[edge] = 1.0f / (1.0f + expf(-acc));
}

extern "C" void kernel_launch(void* const* d_in, const int* in_sizes, int n_in,
                              void* d_out, int out_size, void* d_ws, size_t ws_size,
                              hipStream_t stream) {
    const float* h  = (const float*)d_in[0];
    const void*  ea = d_in[1];
    const void*  eb = d_in[2];
    float* out = (float*)d_out;
    char* ws = (char*)d_ws;

    const int block = 256;

    if (ws_size >= WS_NEED) {
        __half* hh  = (__half*)(ws + H16_OFF);
        int* cursor = (int*)(ws + CURSOR_OFF);
        unsigned long long* packed = (unsigned long long*)(ws + PACKED_OFF);

        hipMemsetAsync(cursor, 0, NB * sizeof(int), stream);

        // capture-safe host queries (no stream ops, deterministic)
        int dev = 0;
        hipGetDevice(&dev);
        int coop = 0, cus = 0, perCU = 0;
        hipDeviceGetAttribute(&coop, hipDeviceAttributeCooperativeLaunch, dev);
        hipDeviceGetAttribute(&cus, hipDeviceAttributeMultiprocessorCount, dev);
        hipOccupancyMaxActiveBlocksPerMultiprocessor(&perCU, fused_all, block, 0);

        bool launched = false;
        if (coop && (long long)cus * perCU >= COOP_BLOCKS) {
            void* args[] = {(void*)&h, (void*)&hh, (void*)&ea, (void*)&eb,
                            (void*)&cursor, (void*)&packed, (void*)&out};
            hipError_t err = hipLaunchCooperativeKernel(
                (const void*)fused_all, dim3(COOP_BLOCKS), dim3(block),
                args, 0, stream);
            launched = (err == hipSuccess);
        }
        if (!launched) {
            pre_kernel<<<PRE_GRID, block, 0, stream>>>(h, hh, ea, eb, cursor, packed);
            edge_main_sorted<<<MAIN_GRID, block, 0, stream>>>(hh, packed, cursor, out);
        }
    } else if (ws_size >= H16_OFF + H16_BYTES) {
        __half* hh = (__half*)(ws + H16_OFF);
        convert_h_fp16<<<CONV_BLOCKS, block, 0, stream>>>(h, hh);
        const long long tt = (long long)NTOT * 8;
        edge_pred_fp16<<<(int)((tt + block - 1) / block), block, 0, stream>>>(hh, ea, eb, out);
    } else {
        const long long tt = (long long)NTOT * 16;
        edge_pred_fp32<<<(int)((tt + block - 1) / block), block, 0, stream>>>(h, ea, eb, out);
    }
}

// Round 10
// 124.825 us; speedup vs baseline: 1.0236x; 1.0236x over previous
//
#include <hip/hip_runtime.h>
#include <hip/hip_fp16.h>

// EdgePredictor: score = sigmoid(dot(h[src], h[dst])) for 2M edges.
// R10 (terminal): best proven deterministic pipeline.
//   D1: convert h->fp16 (25.6MB in ws) + cursor init (extra block).
//   D2: single-pass scatter into 32 fixed-cap src-block buckets
//       (CAP=65536 pow2; 12-sigma slack), packing (s,d,e) 17+17+21b.
//   D3: main gather, 8 lanes/edge, 2 edges/group, XCD-contiguous slices
//       (per-XCD src working set = 4 blocks = 3.2MB < 4MB L2).
// Evidence for this shape:
//   - main is at the ~3.5TB/s random-256B-granule fabric wall: 302MB
//     (246 fetch + 56 write) in 88us; dst misses are compulsory (each XCD
//     touches ~all table rows; 2D bucketing analysis gives no byte cut).
//   - pre overlap attempts all null/regressed: R7 XCD-spread (aliased to
//     XCD0), R8 interleave (byte-bound, not schedule-bound), R9
//     cooperative (slow + capture-nondeterministic -> removed).
//   - R5's simple serial pre (36us) remains the fastest preprocessing.

#define N_NODES 100000
#define D_FEAT  128
#define N_EDGES 1000000
#define NTOT    (2 * N_EDGES)
#define NB      32
#define BLOCK_ROWS ((N_NODES + NB - 1) / NB)   // 3125
#define CAP     65536                           // slots/bucket (pow2)
#define NSLOTS  (NB * CAP)                      // 2,097,152

#define CURSOR_OFF 256                          // int[32]
#define H16_OFF    4096
#define H16_BYTES  ((size_t)N_NODES * D_FEAT * 2)      // 25,600,000
#define PACKED_OFF (H16_OFF + H16_BYTES)                // 16B-aligned
#define PACKED_BYTES ((size_t)NSLOTS * 8)               // 16.8 MB
#define WS_NEED    (PACKED_OFF + PACKED_BYTES)          // ~42.4 MB

#define CONV_ITEMS  (N_NODES * D_FEAT / 8)              // 1,600,000
#define CONV_BLOCKS (CONV_ITEMS / 256)                  // 6250
#define SORT_GRID   ((NTOT + 2047) / 2048)              // 977

typedef float f4v __attribute__((ext_vector_type(4)));

__device__ __forceinline__ int detect64(const void* ea) {
    const long long* p = (const long long*)ea;
    int is64 = 1;
    #pragma unroll
    for (int i = 0; i < 8; ++i) {
        long long v = p[i];
        if (v < 0 || v >= N_NODES) is64 = 0;
    }
    return is64;
}

__device__ __forceinline__ void load_edge(const void* ea, const void* eb,
                                          int is64, long long e,
                                          int& s, int& d) {
    if (e < N_EDGES) {
        if (is64) {
            s = (int)((const long long*)ea)[e];
            d = (int)((const long long*)ea)[e + N_EDGES];
        } else {
            s = ((const int*)ea)[e];
            d = ((const int*)ea)[e + N_EDGES];
        }
    } else {
        long long e2 = e - N_EDGES;
        if (is64) {
            s = (int)((const long long*)eb)[e2];
            d = (int)((const long long*)eb)[e2 + N_EDGES];
        } else {
            s = ((const int*)eb)[e2];
            d = ((const int*)eb)[e2 + N_EDGES];
        }
    }
}

__device__ __forceinline__ void convert8(const float* __restrict__ h,
                                         __half* __restrict__ hh, int i) {
    const float4* src = (const float4*)h;
    float4 a = src[2 * i];
    float4 b = src[2 * i + 1];
    __half2 r[4];
    r[0] = __float22half2_rn(make_float2(a.x, a.y));
    r[1] = __float22half2_rn(make_float2(a.z, a.w));
    r[2] = __float22half2_rn(make_float2(b.x, b.y));
    r[3] = __float22half2_rn(make_float2(b.z, b.w));
    ((float4*)hh)[i] = *(const float4*)r;
}

// ---- D1: fp32->fp16 convert + cursor init (extra block) ----
__global__ __launch_bounds__(256) void convert_and_init(
    const float* __restrict__ h, __half* __restrict__ hh,
    int* __restrict__ cursor) {
    int bid = blockIdx.x;
    if (bid == CONV_BLOCKS) {
        if (threadIdx.x < NB) cursor[threadIdx.x] = threadIdx.x * CAP;
        return;
    }
    convert8(h, hh, bid * 256 + threadIdx.x);
}

// ---- D2: single-pass scatter into fixed-cap buckets (absolute cursor) ----
__global__ __launch_bounds__(256) void scatter_kernel(
    const void* __restrict__ ea, const void* __restrict__ eb,
    int* __restrict__ cursor, unsigned long long* __restrict__ packed) {
    __shared__ int lh[NB];
    __shared__ int lcur[NB];
    int tid = threadIdx.x;
    if (tid < NB) lh[tid] = 0;
    __syncthreads();
    const int is64 = detect64(ea);
    long long base = (long long)blockIdx.x * 2048;
    int ss[8], dd[8], ee[8];
    int cnt = 0;
    #pragma unroll
    for (int i = 0; i < 8; ++i) {
        long long e = base + i * 256 + tid;
        if (e >= NTOT) break;
        int s, d;
        load_edge(ea, eb, is64, e, s, d);
        ss[cnt] = s; dd[cnt] = d; ee[cnt] = (int)e; ++cnt;
        atomicAdd(&lh[s / BLOCK_ROWS], 1);
    }
    __syncthreads();
    if (tid < NB)
        lcur[tid] = atomicAdd(&cursor[tid], lh[tid]);   // absolute position
    __syncthreads();
    for (int i = 0; i < cnt; ++i) {
        int b = ss[i] / BLOCK_ROWS;
        int pos = atomicAdd(&lcur[b], 1);
        packed[pos] = (unsigned long long)ss[i]
                    | ((unsigned long long)dd[i] << 17)
                    | ((unsigned long long)ee[i] << 34);
    }
}

// ---- D3: main gather, 8 lanes/edge, 2 edges/group ----
#define MAIN_GRID (NSLOTS / 64)                // 32768 blocks
#define GRID_PER_XCD (MAIN_GRID / 8)           // 4096

__device__ __forceinline__ float dot8_f16(f4v sv, f4v dv, float acc) {
    const __half2* s2 = (const __half2*)&sv;
    const __half2* d2 = (const __half2*)&dv;
#if __has_builtin(__builtin_amdgcn_fdot2)
    #pragma unroll
    for (int j = 0; j < 4; ++j)
        acc = __builtin_amdgcn_fdot2(s2[j], d2[j], acc, false);
#else
    #pragma unroll
    for (int j = 0; j < 4; ++j) {
        float2 sf = __half22float2(s2[j]);
        float2 df = __half22float2(d2[j]);
        acc += sf.x * df.x + sf.y * df.y;
    }
#endif
    return acc;
}

__global__ __launch_bounds__(256) void edge_main_sorted(
    const __half* __restrict__ hh,
    const unsigned long long* __restrict__ packed,
    const int* __restrict__ cursor,       // absolute end per bucket
    float* __restrict__ out) {
    // round-robin inverse: each XCD gets a contiguous 1/8 of slots
    int bid = blockIdx.x;
    int swz = (bid & 7) * GRID_PER_XCD + (bid >> 3);
    int gid = swz * 256 + threadIdx.x;
    int grp  = gid >> 3;
    int lane = gid & 7;
    int slot0 = grp << 1;                 // even; pair never straddles buckets
    int b = slot0 >> 16;                  // CAP = 2^16
    int end = cursor[b];                  // absolute end position
    if (slot0 >= end) return;             // tail holes (group-uniform exit)
    bool v1 = (slot0 + 1) < end;

    ulonglong2 pp = *(const ulonglong2*)(packed + slot0);
    unsigned long long p0 = pp.x;
    unsigned long long p1 = v1 ? pp.y : pp.x;   // dup edge0 if hole (no store)
    int s0 = (int)(p0 & 0x1FFFF), d0 = (int)((p0 >> 17) & 0x1FFFF), e0 = (int)(p0 >> 34);
    int s1 = (int)(p1 & 0x1FFFF), d1 = (int)((p1 >> 17) & 0x1FFFF), e1 = (int)(p1 >> 34);

    const f4v* ps0 = (const f4v*)(hh + (size_t)s0 * D_FEAT) + lane * 2;
    const f4v* pd0 = (const f4v*)(hh + (size_t)d0 * D_FEAT) + lane * 2;
    const f4v* ps1 = (const f4v*)(hh + (size_t)s1 * D_FEAT) + lane * 2;
    const f4v* pd1 = (const f4v*)(hh + (size_t)d1 * D_FEAT) + lane * 2;
    f4v sa0 = ps0[0], sb0 = ps0[1];
    f4v da0 = pd0[0], db0 = pd0[1];
    f4v sa1 = ps1[0], sb1 = ps1[1];
    f4v da1 = pd1[0], db1 = pd1[1];

    float acc0 = dot8_f16(sb0, db0, dot8_f16(sa0, da0, 0.0f));
    float acc1 = dot8_f16(sb1, db1, dot8_f16(sa1, da1, 0.0f));
    acc0 += __shfl_xor(acc0, 4, 64);
    acc0 += __shfl_xor(acc0, 2, 64);
    acc0 += __shfl_xor(acc0, 1, 64);
    acc1 += __shfl_xor(acc1, 4, 64);
    acc1 += __shfl_xor(acc1, 2, 64);
    acc1 += __shfl_xor(acc1, 1, 64);

    if (lane == 0) {
        out[e0] = 1.0f / (1.0f + expf(-acc0));
        if (v1) out[e1] = 1.0f / (1.0f + expf(-acc1));
    }
}

// ---- fallback (ws fits h16 only): unsorted fp16 ----
__global__ __launch_bounds__(256) void convert_h_fp16(
    const float* __restrict__ h, __half* __restrict__ hh) {
    int i = blockIdx.x * 256 + threadIdx.x;
    if (i >= CONV_ITEMS) return;
    convert8(h, hh, i);
}

__global__ __launch_bounds__(256) void edge_pred_fp16(
    const __half* __restrict__ hh,
    const void* __restrict__ ea, const void* __restrict__ eb,
    float* __restrict__ out) {
    int gid  = blockIdx.x * 256 + threadIdx.x;
    int edge = gid >> 3;
    int lane = gid & 7;
    if (edge >= NTOT) return;
    const int is64 = detect64(ea);
    int s, d;
    load_edge(ea, eb, is64, (long long)edge, s, d);
    const f4v* ps = (const f4v*)(hh + (size_t)s * D_FEAT) + lane * 2;
    const f4v* pd = (const f4v*)(hh + (size_t)d * D_FEAT) + lane * 2;
    f4v s0 = ps[0], s1 = ps[1], d0 = pd[0], d1 = pd[1];
    float acc = dot8_f16(s1, d1, dot8_f16(s0, d0, 0.0f));
    acc += __shfl_xor(acc, 4, 64);
    acc += __shfl_xor(acc, 2, 64);
    acc += __shfl_xor(acc, 1, 64);
    if (lane == 0)
        out[edge] = 1.0f / (1.0f + expf(-acc));
}

// ---- fallback (no ws): fp32 ----
__global__ __launch_bounds__(256) void edge_pred_fp32(
    const float* __restrict__ h,
    const void* __restrict__ ea, const void* __restrict__ eb,
    float* __restrict__ out) {
    int gid  = blockIdx.x * 256 + threadIdx.x;
    int edge = gid >> 4;
    int lane = gid & 15;
    if (edge >= NTOT) return;
    const int is64 = detect64(ea);
    int s, d;
    load_edge(ea, eb, is64, (long long)edge, s, d);
    const float4* ps = (const float4*)(h + (size_t)s * D_FEAT) + lane * 2;
    const float4* pd = (const float4*)(h + (size_t)d * D_FEAT) + lane * 2;
    float4 s0 = ps[0], s1 = ps[1], d0 = pd[0], d1 = pd[1];
    float acc = s0.x * d0.x + s0.y * d0.y + s0.z * d0.z + s0.w * d0.w
              + s1.x * d1.x + s1.y * d1.y + s1.z * d1.z + s1.w * d1.w;
    #pragma unroll
    for (int off = 8; off >= 1; off >>= 1)
        acc += __shfl_xor(acc, off, 64);
    if (lane == 0)
        out[edge] = 1.0f / (1.0f + expf(-acc));
}

extern "C" void kernel_launch(void* const* d_in, const int* in_sizes, int n_in,
                              void* d_out, int out_size, void* d_ws, size_t ws_size,
                              hipStream_t stream) {
    const float* h  = (const float*)d_in[0];
    const void*  ea = d_in[1];
    const void*  eb = d_in[2];
    float* out = (float*)d_out;
    char* ws = (char*)d_ws;

    const int block = 256;

    if (ws_size >= WS_NEED) {
        __half* hh  = (__half*)(ws + H16_OFF);
        int* cursor = (int*)(ws + CURSOR_OFF);
        unsigned long long* packed = (unsigned long long*)(ws + PACKED_OFF);

        convert_and_init<<<CONV_BLOCKS + 1, block, 0, stream>>>(h, hh, cursor);
        scatter_kernel<<<SORT_GRID, block, 0, stream>>>(ea, eb, cursor, packed);
        edge_main_sorted<<<MAIN_GRID, block, 0, stream>>>(hh, packed, cursor, out);
    } else if (ws_size >= H16_OFF + H16_BYTES) {
        __half* hh = (__half*)(ws + H16_OFF);
        convert_h_fp16<<<CONV_BLOCKS, block, 0, stream>>>(h, hh);
        const long long tt = (long long)NTOT * 8;
        edge_pred_fp16<<<(int)((tt + block - 1) / block), block, 0, stream>>>(hh, ea, eb, out);
    } else {
        const long long tt = (long long)NTOT * 16;
        edge_pred_fp32<<<(int)((tt + block - 1) / block), block, 0, stream>>>(h, ea, eb, out);
    }
}